// Round 11
// baseline (102.479 us; speedup 1.0000x reference)
//
#include <hip/hip_runtime.h>
#include <math.h>
#include <cstddef>

#define BB 2
#define SSEQ 2048
#define HH 16
#define DD 64
#define ROW 3072              // floats per (b,s) row = 3*H*D
#define TT 64                 // t-tile per block
#define SCH 64                // s-chunk
#define LSTR 72               // f16 elems/row for all LDS tiles (144 B, 16B-aligned)

typedef __attribute__((ext_vector_type(8))) _Float16 half8;
typedef __attribute__((ext_vector_type(4))) _Float16 half4;
typedef __attribute__((ext_vector_type(4))) float floatx4;

// Stick-breaking attention, all-f16 MFMA datapath (err budget: threshold 9.4e-2;
// f16 QK ~7e-4 score err, f16 sp-scan ~7e-3, f16 att/V PV ~2e-3 -> ~0.01 total):
//   QK^T f16 (8 MFMA, Q A-frags register-resident) -> sp = softplus in regs
//   -> sp f16 LDS round-trip (wave-private stripe) -> rev = sp*M via constant
//   register B-frags (8 MFMA) + carry via B=ones (2) -> att = exp(x-sp-rev-C)
//   -> att f16 overlays sp stripe -> PV (8 MFMA) + row-sums via ones (2).
// 2 barriers/chunk (K/V staging only); no shuffles/atomics. LDS 27.7 KB,
// 4 blocks/CU co-resident (grid = 4 blocks/CU exactly).
__global__ __launch_bounds__(256, 4) void sb_attn_f16(const float* __restrict__ qkv,
                                                      float* __restrict__ out) {
    __shared__ alignas(16) _Float16 Kf[SCH * LSTR];   // K[s][d]
    __shared__ alignas(16) _Float16 Vt[DD * LSTR];    // V^T[d][s]
    __shared__ alignas(16) _Float16 spf[TT * LSTR];   // sp then att (wave-private stripes)
    __shared__ int wdone[4];

    const int tid  = threadIdx.x;
    const int w    = tid >> 6;
    const int lane = tid & 63;
    const int m    = lane & 15;       // MFMA row (A) / col (B,C)
    const int q    = lane >> 4;       // MFMA quad
    const int wrow = w * 16;          // wave's t-stripe [wrow, wrow+16)
    const int g    = tid >> 4;        // staging row group
    const int li   = tid & 15;

    const int bh = blockIdx.x >> 5;
    const int h  = bh & (HH - 1);
    const int b  = bh >> 4;
    const int T0 = (blockIdx.x & 31) * TT;

    const float scale = 0.1875f;      // 1.5/sqrt(64)
    const float* qb = qkv + (size_t)b * SSEQ * ROW + h * DD;
    const float* kb = qb + HH * DD;
    const float* vb = qb + 2 * HH * DD;

    // ---- Q A-frags straight to registers: row T0+wrow+m, k = ks*32 + q*8 .. +7
    half8 Aq[2];
    #pragma unroll
    for (int ks = 0; ks < 2; ++ks) {
        const float* qp = &qb[(size_t)(T0 + wrow + m) * ROW + ks * 32 + q * 8];
        float4 a = *(const float4*)qp;
        float4 c = *(const float4*)(qp + 4);
        half8 v;
        v[0] = (_Float16)(a.x * scale); v[1] = (_Float16)(a.y * scale);
        v[2] = (_Float16)(a.z * scale); v[3] = (_Float16)(a.w * scale);
        v[4] = (_Float16)(c.x * scale); v[5] = (_Float16)(c.y * scale);
        v[6] = (_Float16)(c.z * scale); v[7] = (_Float16)(c.w * scale);
        Aq[ks] = v;
    }
    if (tid < 4) wdone[tid] = 0;

    // ---- constant B-frags: M (strict upper tri) and ones, f16
    const _Float16 ONEH = (_Float16)1.0f;
    half8 onesf;
    #pragma unroll
    for (int j = 0; j < 8; ++j) onesf[j] = ONEH;
    half8 Mfrag[2][4];
    #pragma unroll
    for (int ks = 0; ks < 2; ++ks)
        #pragma unroll
        for (int n = 0; n < 4; ++n)
            #pragma unroll
            for (int j = 0; j < 8; ++j)
                Mfrag[ks][n][j] = ((ks * 32 + q * 8 + j) > (n * 16 + m)) ? ONEH : (_Float16)0.0f;

    floatx4 oac[4] = {{0,0,0,0},{0,0,0,0},{0,0,0,0},{0,0,0,0}};
    floatx4 ctotAcc = {0,0,0,0};   // running softplus carry C per row
    floatx4 asumAcc = {0,0,0,0};   // running att row-sum

    _Float16* attA = &spf[wrow * LSTR];  // wave-private stripe (16 rows)

    int chunk = 0;
    for (int S0 = T0; S0 >= 0; S0 -= SCH, ++chunk) {
        __syncthreads();   // B1: prev PV done with Kf/Vt; wdone visible
        if (chunk > 0 && (wdone[0] & wdone[1] & wdone[2] & wdone[3])) break;

        // ---- stage K (f16): row g*4+rr, cols li*4..+3
        #pragma unroll
        for (int rr = 0; rr < 4; ++rr) {
            const int r = g * 4 + rr;
            float4 v4 = *(const float4*)&kb[(size_t)(S0 + r) * ROW + li * 4];
            half4 hv = {(_Float16)v4.x, (_Float16)v4.y, (_Float16)v4.z, (_Float16)v4.w};
            *(half4*)&Kf[r * LSTR + li * 4] = hv;
        }
        // ---- stage V^T (f16): d = lane, s = w*16 + u*4 .. +3
        #pragma unroll
        for (int u = 0; u < 4; ++u) {
            const int s0v = w * 16 + u * 4;
            float a0 = vb[(size_t)(S0 + s0v + 0) * ROW + lane];
            float a1 = vb[(size_t)(S0 + s0v + 1) * ROW + lane];
            float a2 = vb[(size_t)(S0 + s0v + 2) * ROW + lane];
            float a3 = vb[(size_t)(S0 + s0v + 3) * ROW + lane];
            half4 hv = {(_Float16)a0, (_Float16)a1, (_Float16)a2, (_Float16)a3};
            *(half4*)&Vt[lane * LSTR + s0v] = hv;
        }
        __syncthreads();   // B2: tiles staged

        // ---- QK^T: 8 MFMAs (2 ksteps x 4 col-tiles)
        floatx4 acc[4] = {{0,0,0,0},{0,0,0,0},{0,0,0,0},{0,0,0,0}};
        #pragma unroll
        for (int ks = 0; ks < 2; ++ks) {
            const int ko = ks * 32 + q * 8;
            #pragma unroll
            for (int n = 0; n < 4; ++n) {
                half8 Bv = *(const half8*)&Kf[(n * 16 + m) * LSTR + ko];
                acc[n] = __builtin_amdgcn_mfma_f32_16x16x32_f16(Aq[ks], Bv, acc[n], 0, 0, 0);
            }
        }

        // ---- sp = softplus(x) masked -> f16 LDS (C-layout addr, wave-private rows)
        float spv[4][4];
        #pragma unroll
        for (int n = 0; n < 4; ++n) {
            #pragma unroll
            for (int reg = 0; reg < 4; ++reg) {
                const int row = wrow + q * 4 + reg;
                const bool valid = (S0 + n * 16 + m) < (T0 + row);
                const float s = valid ? __logf(1.f + __expf(acc[n][reg])) : 0.f;
                spv[n][reg] = s;
                spf[row * LSTR + n * 16 + m] = (_Float16)s;
            }
        }

        // ---- sp A-frags (row = wrow+m)
        half8 SA[2];
        #pragma unroll
        for (int ks = 0; ks < 2; ++ks)
            SA[ks] = *(const half8*)&spf[(wrow + m) * LSTR + ks * 32 + q * 8];

        const float Cold[4] = {ctotAcc[0], ctotAcc[1], ctotAcc[2], ctotAcc[3]};

        // ---- scan: rev = sp * M (8 MFMA); C += row-total via ones (2 MFMA)
        floatx4 rev[4] = {{0,0,0,0},{0,0,0,0},{0,0,0,0},{0,0,0,0}};
        #pragma unroll
        for (int ks = 0; ks < 2; ++ks) {
            #pragma unroll
            for (int n = 0; n < 4; ++n)
                rev[n] = __builtin_amdgcn_mfma_f32_16x16x32_f16(SA[ks], Mfrag[ks][n], rev[n], 0, 0, 0);
            ctotAcc = __builtin_amdgcn_mfma_f32_16x16x32_f16(SA[ks], onesf, ctotAcc, 0, 0, 0);
        }

        // ---- att = exp(x - sp - rev - C) -> f16, overlays sp stripe
        #pragma unroll
        for (int n = 0; n < 4; ++n) {
            #pragma unroll
            for (int reg = 0; reg < 4; ++reg) {
                const int row = q * 4 + reg;
                const bool valid = (S0 + n * 16 + m) < (T0 + wrow + row);
                const float y = acc[n][reg] - spv[n][reg] - rev[n][reg] - Cold[reg];
                attA[row * LSTR + n * 16 + m] = valid ? (_Float16)__expf(y) : (_Float16)0.0f;
            }
        }

        // ---- PV (8 MFMA) + att row-sums via ones (2 MFMA)
        #pragma unroll
        for (int ks = 0; ks < 2; ++ks) {
            const int ko = ks * 32 + q * 8;
            half8 Ap = *(const half8*)&attA[m * LSTR + ko];
            asumAcc = __builtin_amdgcn_mfma_f32_16x16x32_f16(Ap, onesf, asumAcc, 0, 0, 0);
            #pragma unroll
            for (int n = 0; n < 4; ++n) {
                half8 Bv = *(const half8*)&Vt[(n * 16 + m) * LSTR + ko];
                oac[n] = __builtin_amdgcn_mfma_f32_16x16x32_f16(Ap, Bv, oac[n], 0, 0, 0);
            }
        }

        // ---- done flag (monotone)
        const bool myd = (ctotAcc[0] > 30.f) && (ctotAcc[1] > 30.f) &&
                         (ctotAcc[2] > 30.f) && (ctotAcc[3] > 30.f);
        const int wd = __all((int)myd);
        if (lane == 0) wdone[w] = wd;
    }

    // ---- epilogue: out = oac + (1 - asum) * v_t
    #pragma unroll
    for (int n = 0; n < 4; ++n) {
        #pragma unroll
        for (int reg = 0; reg < 4; ++reg) {
            const int tl = wrow + q * 4 + reg;
            const int tG = T0 + tl;
            const int dc = n * 16 + m;
            const float rem = 1.f - asumAcc[reg];
            const float vt = vb[(size_t)tG * ROW + dc];
            out[(((size_t)b * SSEQ + tG) * HH + h) * DD + dc] = fmaf(rem, vt, oac[n][reg]);
        }
    }
}

extern "C" void kernel_launch(void* const* d_in, const int* in_sizes, int n_in,
                              void* d_out, int out_size, void* d_ws, size_t ws_size,
                              hipStream_t stream) {
    const float* qkv = (const float*)d_in[0];
    float* out = (float*)d_out;
    const int blocks = BB * HH * (SSEQ / TT);   // 1024
    sb_attn_f16<<<blocks, 256, 0, stream>>>(qkv, out);
}